// Round 1
// baseline (284.438 us; speedup 1.0000x reference)
//
#include <hip/hip_runtime.h>

#define S_DIM 512
#define H_DIM 512
#define NH 256      // H/2
#define TI 16
#define TJ 8
#define MB 128      // TI*TJ
#define BK 64

#define AS1 __attribute__((address_space(1)))
#define AS3 __attribute__((address_space(3)))

typedef _Float16 half8 __attribute__((ext_vector_type(8)));
typedef float f32x4 __attribute__((ext_vector_type(4)));

// ---------------- kernel 1: W2 [512,256] fp32 -> W2^T [256,512] f16 ----------------
__global__ __launch_bounds__(256) void convert_w2_kernel(const float* __restrict__ W2,
                                                         _Float16* __restrict__ w2T) {
    int t = blockIdx.x * 256 + threadIdx.x;   // 16384 threads
    int n  = t >> 6;                          // 0..255
    int kc = t & 63;                          // 8-elem k chunk
    int k0 = kc * 8;
    half8 v;
#pragma unroll
    for (int i = 0; i < 8; i++) v[i] = (_Float16)W2[(k0 + i) * NH + n];
    *(half8*)&w2T[n * H_DIM + k0] = v;
}

// ---------------- kernel 2: a' = feats@W1[:H]+b1 ; c = feats@W1[H:]  (f16 out) -----
__global__ __launch_bounds__(256) void prep_kernel(const float* __restrict__ feats,
                                                   const float* __restrict__ W1,
                                                   const float* __restrict__ b1,
                                                   _Float16* __restrict__ aH,
                                                   _Float16* __restrict__ cH) {
    const int half_id = blockIdx.z;
    const float* Wb = W1 + half_id * H_DIM * H_DIM;
    _Float16* outp = half_id ? cH : aH;
    const int M0 = blockIdx.y * 64, N0 = blockIdx.x * 64;
    __shared__ float As[64][36];   // stride 36: 16B-aligned rows, 4-bank shift
    __shared__ float Bs[32][64];
    const int tid = threadIdx.x;
    const int tx = tid & 15, ty = tid >> 4;
    float racc[4][4] = {};
    for (int k0 = 0; k0 < H_DIM; k0 += 32) {
        {
            int row = tid >> 2, ch = tid & 3;
            const float4* g = (const float4*)&feats[(M0 + row) * H_DIM + k0 + ch * 8];
            float4 v0 = g[0], v1 = g[1];
            *(float4*)&As[row][ch * 8]     = v0;
            *(float4*)&As[row][ch * 8 + 4] = v1;
            int rb = tid >> 3, cb = tid & 7;
            const float4* gb = (const float4*)&Wb[(k0 + rb) * H_DIM + N0 + cb * 8];
            float4 w0 = gb[0], w1 = gb[1];
            *(float4*)&Bs[rb][cb * 8]     = w0;
            *(float4*)&Bs[rb][cb * 8 + 4] = w1;
        }
        __syncthreads();
#pragma unroll
        for (int k = 0; k < 32; k++) {
            float4 bv = *(float4*)&Bs[k][tx * 4];
            float a0[4];
#pragma unroll
            for (int i = 0; i < 4; i++) a0[i] = As[ty * 4 + i][k];
#pragma unroll
            for (int i = 0; i < 4; i++) {
                racc[i][0] += a0[i] * bv.x;
                racc[i][1] += a0[i] * bv.y;
                racc[i][2] += a0[i] * bv.z;
                racc[i][3] += a0[i] * bv.w;
            }
        }
        __syncthreads();
    }
#pragma unroll
    for (int i = 0; i < 4; i++) {
        int m = M0 + ty * 4 + i;
#pragma unroll
        for (int j = 0; j < 4; j++) {
            int n = N0 + tx * 4 + j;
            float v = racc[i][j] + (half_id == 0 ? b1[n] : 0.f);
            outp[m * H_DIM + n] = (_Float16)v;
        }
    }
}

// ---------------- kernel 3: pair GEMM + fused epilogue -----------------------------
// grid (S/TJ=64, S/TI=32, B). block 512 = 8 waves (2 along M, 4 along N).
// LDS rows hold XOR-swizzled 16B chunks so global_load_lds (contiguous) and
// ds_read_b128 (2-way conflict, free) coexist.
__global__ __launch_bounds__(512) void pair_kernel(
        const _Float16* __restrict__ aH, const _Float16* __restrict__ cH,
        const _Float16* __restrict__ w2T,
        const float* __restrict__ b2, const float* __restrict__ W3,
        const float* __restrict__ b3, float* __restrict__ out) {
    const int jt = blockIdx.x, it = blockIdx.y, b = blockIdx.z;
    const int i0 = it * TI, j0 = jt * TJ;

    __shared__ __align__(16) _Float16 sa[TI * H_DIM];   // 16 KB
    __shared__ __align__(16) _Float16 sc[TJ * H_DIM];   //  8 KB
    __shared__ __align__(16) _Float16 sw[256 * BK];     // 32 KB
    __shared__ float spart[4][MB];                      //  2 KB

    const int tid = threadIdx.x;
    const int wave = tid >> 6, lane = tid & 63;
    const int quad = lane >> 4, l16 = lane & 15;
    const int wm = wave >> 2, wn = wave & 3;
    const int rb = wm * 64, nb = wn * 64;

    // ---- stage a rows (16) and c rows (8), full K, swizzled, async ----
    for (int rr = wave; rr < TI; rr += 8) {
        int gc = (lane & ~7) | ((lane & 7) ^ (rr & 7));
        const _Float16* g = &aH[((size_t)(b * S_DIM + i0 + rr)) * H_DIM + gc * 8];
        __builtin_amdgcn_global_load_lds((const AS1 unsigned int*)g,
                                         (AS3 unsigned int*)&sa[rr * H_DIM], 16, 0, 0);
    }
    if (wave < TJ) {
        int rr = wave;
        int gc = (lane & ~7) | ((lane & 7) ^ (rr & 7));
        const _Float16* g = &cH[((size_t)(b * S_DIM + j0 + rr)) * H_DIM + gc * 8];
        __builtin_amdgcn_global_load_lds((const AS1 unsigned int*)g,
                                         (AS3 unsigned int*)&sc[rr * H_DIM], 16, 0, 0);
    }

    // row -> (a-row, c-row) for each of this wave's 4 m-tiles
    int ilrow[4], jlrow[4];
#pragma unroll
    for (int mt = 0; mt < 4; mt++) {
        int r = rb + mt * 16 + l16;
        ilrow[mt] = r >> 3;
        jlrow[mt] = r & 7;
    }

    f32x4 acc[4][4];
#pragma unroll
    for (int mt = 0; mt < 4; mt++)
#pragma unroll
        for (int nt = 0; nt < 4; nt++) acc[mt][nt] = (f32x4)0.f;

    // W2^T tile stager: 256 rows x 64 k (f16), rows of 8 chunks, chunk XOR row&7
    auto stage_w = [&](int ko) {
#pragma unroll
        for (int is = 0; is < 4; is++) {
            int r0 = is * 64 + wave * 8;
            int r = r0 + (lane >> 3);
            int gc = (lane & 7) ^ (r & 7);
            const _Float16* g = &w2T[(size_t)r * H_DIM + ko * BK + gc * 8];
            __builtin_amdgcn_global_load_lds((const AS1 unsigned int*)g,
                                             (AS3 unsigned int*)&sw[r0 * BK], 16, 0, 0);
        }
    };

    stage_w(0);

    for (int ko = 0; ko < 8; ko++) {
        __syncthreads();   // vmcnt(0) drain: sw tile ko (and sa/sc on first iter) ready
#pragma unroll
        for (int kr = 0; kr < 2; kr++) {
            const int gcb = ko * 8 + kr * 4 + quad;      // global 8-elem chunk of k
            half8 afrag[4];
#pragma unroll
            for (int mt = 0; mt < 4; mt++) {
                int slotA = (gcb & ~7) | ((gcb & 7) ^ (ilrow[mt] & 7));
                int slotC = (gcb & ~7) | ((gcb & 7) ^ (jlrow[mt] & 7));
                half8 va = *(const half8*)&sa[ilrow[mt] * H_DIM + slotA * 8];
                half8 vc = *(const half8*)&sc[jlrow[mt] * H_DIM + slotC * 8];
                half8 h = va + vc;
#pragma unroll
                for (int e = 0; e < 8; e++)
                    h[e] = h[e] > (_Float16)0.f ? h[e] : (_Float16)0.f;
                afrag[mt] = h;
            }
#pragma unroll
            for (int nt = 0; nt < 4; nt++) {
                int n = nb + nt * 16 + l16;
                int cslot = (kr * 4 + quad) ^ (n & 7);
                half8 bfrag = *(const half8*)&sw[n * BK + cslot * 8];
#pragma unroll
                for (int mt = 0; mt < 4; mt++)
                    acc[mt][nt] = __builtin_amdgcn_mfma_f32_16x16x32_f16(
                        afrag[mt], bfrag, acc[mt][nt], 0, 0, 0);
            }
        }
        __syncthreads();   // all waves done reading sw
        if (ko < 7) stage_w(ko + 1);
    }

    // ---- fused epilogue: h2 = relu(acc+b2); partial logit = h2 . W3 ----
    float b2v[4], w3v[4];
#pragma unroll
    for (int nt = 0; nt < 4; nt++) {
        int n = nb + nt * 16 + l16;
        b2v[nt] = b2[n];
        w3v[nt] = W3[n];
    }
    float ps[4][4];
#pragma unroll
    for (int mt = 0; mt < 4; mt++)
#pragma unroll
        for (int r = 0; r < 4; r++) {
            float s = 0.f;
#pragma unroll
            for (int nt = 0; nt < 4; nt++) {
                float v = acc[mt][nt][r] + b2v[nt];
                v = v > 0.f ? v : 0.f;
                s += v * w3v[nt];
            }
            ps[mt][r] = s;
        }
    // reduce over the 16 columns held across lanes l16 (groups of 16)
#pragma unroll
    for (int mt = 0; mt < 4; mt++)
#pragma unroll
        for (int r = 0; r < 4; r++) {
            float s = ps[mt][r];
            s += __shfl_xor(s, 8, 16);
            s += __shfl_xor(s, 4, 16);
            s += __shfl_xor(s, 2, 16);
            s += __shfl_xor(s, 1, 16);
            ps[mt][r] = s;
        }
    if (l16 == 0) {
#pragma unroll
        for (int mt = 0; mt < 4; mt++)
#pragma unroll
            for (int r = 0; r < 4; r++)
                spart[wn][rb + mt * 16 + quad * 4 + r] = ps[mt][r];
    }
    __syncthreads();
    if (tid < MB) {
        float tot = spart[0][tid] + spart[1][tid] + spart[2][tid] + spart[3][tid] + b3[0];
        float sg = 1.f / (1.f + __expf(-tot));
        int i = i0 + (tid >> 3), j = j0 + (tid & 7);
        out[(size_t)b * S_DIM * S_DIM + (size_t)i * S_DIM + j] = sg;
    }
}

extern "C" void kernel_launch(void* const* d_in, const int* in_sizes, int n_in,
                              void* d_out, int out_size, void* d_ws, size_t ws_size,
                              hipStream_t stream) {
    const float* feats = (const float*)d_in[0];
    const float* W1 = (const float*)d_in[1];
    const float* b1 = (const float*)d_in[2];
    const float* W2 = (const float*)d_in[3];
    const float* b2 = (const float*)d_in[4];
    const float* W3 = (const float*)d_in[5];
    const float* b3 = (const float*)d_in[6];
    float* out = (float*)d_out;

    const int B = in_sizes[0] / (S_DIM * H_DIM);   // = 2

    char* ws = (char*)d_ws;
    _Float16* aH  = (_Float16*)ws;                  // [B*S][H] f16 = 1 MB
    _Float16* cH  = (_Float16*)(ws + (1 << 20));    // [B*S][H] f16 = 1 MB
    _Float16* w2T = (_Float16*)(ws + (2 << 20));    // [256][512] f16 = 256 KB

    convert_w2_kernel<<<64, 256, 0, stream>>>(W2, w2T);
    prep_kernel<<<dim3(H_DIM / 64, B * S_DIM / 64, 2), 256, 0, stream>>>(feats, W1, b1, aH, cH);
    pair_kernel<<<dim3(S_DIM / TJ, S_DIM / TI, B), 512, 0, stream>>>(aH, cH, w2T, b2, W3, b3, out);
}

// Round 2
// 229.316 us; speedup vs baseline: 1.2404x; 1.2404x over previous
//
#include <hip/hip_runtime.h>

#define S_DIM 512
#define H_DIM 512
#define NH 256
#define TI 8
#define TJ 8

#define AS1 __attribute__((address_space(1)))
#define AS3 __attribute__((address_space(3)))

typedef _Float16 half8 __attribute__((ext_vector_type(8)));
typedef _Float16 half4 __attribute__((ext_vector_type(4)));
typedef float f32x4 __attribute__((ext_vector_type(4)));

// ---------------- k0: feats fp32 -> f16 ----------------
__global__ __launch_bounds__(256) void convert_feats_kernel(const float* __restrict__ f,
                                                            _Float16* __restrict__ o) {
    int t = blockIdx.x * 256 + threadIdx.x;   // 131072 threads, 4 elems each
    float4 v = ((const float4*)f)[t];
    half4 h;
    h.x = (_Float16)v.x; h.y = (_Float16)v.y; h.z = (_Float16)v.z; h.w = (_Float16)v.w;
    ((half4*)o)[t] = h;
}

// ---------------- k1: W1 [1024,512] fp32 -> fragment-major f16 w1L[gcb][n]{8} ------
// chunk(gcb, n)[j] = Bw1[k=gcb*8+j][n],  Bw1[k][n] = n<512 ? W1[k][n] : W1[512+k][n-512]
__global__ __launch_bounds__(256) void convert_w1_kernel(const float* __restrict__ W1,
                                                         _Float16* __restrict__ w1L) {
    int t = blockIdx.x * 256 + threadIdx.x;   // 65536
    int gcb = t >> 10, n = t & 1023;
    const float* src = (n < H_DIM) ? &W1[(size_t)(gcb * 8) * H_DIM + n]
                                   : &W1[(size_t)(H_DIM + gcb * 8) * H_DIM + (n - H_DIM)];
    half8 v;
#pragma unroll
    for (int j = 0; j < 8; j++) v[j] = (_Float16)src[(size_t)j * H_DIM];
    *(half8*)&w1L[((size_t)gcb * 1024 + n) * 8] = v;
}

// ---------------- k2: W2 [512,256] fp32 -> fragment-major f16 w2L[gcb][n]{8} -------
__global__ __launch_bounds__(256) void convert_w2_kernel(const float* __restrict__ W2,
                                                         _Float16* __restrict__ w2L) {
    int t = blockIdx.x * 256 + threadIdx.x;   // 16384
    int gcb = t >> 8, n = t & 255;
    half8 v;
#pragma unroll
    for (int j = 0; j < 8; j++) v[j] = (_Float16)W2[(size_t)(gcb * 8 + j) * NH + n];
    *(half8*)&w2L[((size_t)gcb * 256 + n) * 8] = v;
}

// ---------------- k3: prep GEMM  [1024 x 512] @ [512 x 1024] f16 MFMA --------------
// out cols 0..511 -> aH (+b1), 512..1023 -> cH
__global__ __launch_bounds__(256) void prep_mfma_kernel(const _Float16* __restrict__ f16,
        const _Float16* __restrict__ w1L, const float* __restrict__ b1,
        _Float16* __restrict__ aH, _Float16* __restrict__ cH) {
    const int n0 = blockIdx.x * 64, m0 = blockIdx.y * 64;
    const int tid = threadIdx.x, wave = tid >> 6, lane = tid & 63;
    const int quad = lane >> 4, l16 = lane & 15;
    const int wm = wave >> 1, wn = wave & 1;
    int mrow[2], ncol[2];
#pragma unroll
    for (int mt = 0; mt < 2; mt++) mrow[mt] = m0 + wm * 32 + mt * 16 + l16;
#pragma unroll
    for (int nt = 0; nt < 2; nt++) ncol[nt] = n0 + wn * 32 + nt * 16 + l16;
    f32x4 acc[2][2];
#pragma unroll
    for (int mt = 0; mt < 2; mt++)
#pragma unroll
        for (int nt = 0; nt < 2; nt++) acc[mt][nt] = (f32x4)0.f;
#pragma unroll
    for (int ks = 0; ks < 16; ks++) {
        int gcb = ks * 4 + quad;
        half8 af[2], bf[2];
#pragma unroll
        for (int mt = 0; mt < 2; mt++)
            af[mt] = *(const half8*)&f16[(size_t)mrow[mt] * H_DIM + gcb * 8];
#pragma unroll
        for (int nt = 0; nt < 2; nt++)
            bf[nt] = *(const half8*)&w1L[((size_t)gcb * 1024 + ncol[nt]) * 8];
#pragma unroll
        for (int nt = 0; nt < 2; nt++)
#pragma unroll
            for (int mt = 0; mt < 2; mt++)
                acc[mt][nt] = __builtin_amdgcn_mfma_f32_16x16x32_f16(af[mt], bf[nt],
                                                                     acc[mt][nt], 0, 0, 0);
    }
    const bool first_half = (n0 < H_DIM);
#pragma unroll
    for (int nt = 0; nt < 2; nt++) {
        float bias = first_half ? b1[ncol[nt]] : 0.f;
#pragma unroll
        for (int mt = 0; mt < 2; mt++)
#pragma unroll
            for (int r = 0; r < 4; r++) {
                int m = m0 + wm * 32 + mt * 16 + quad * 4 + r;
                float v = acc[mt][nt][r] + bias;
                if (first_half) aH[(size_t)m * H_DIM + ncol[nt]] = (_Float16)v;
                else            cH[(size_t)m * H_DIM + (ncol[nt] - H_DIM)] = (_Float16)v;
            }
    }
}

// ---------------- k4: pair GEMM, barrier-free K-loop, B from global ----------------
// grid (S/TJ=64, S/TI=64, B). block 256 = 4 waves, all wn (N split 4x64), wave tile 64x64.
// Block M-tile = 64 pairs = 8 i-rows x 8 j-rows.
__global__ __launch_bounds__(256, 3) void pair_kernel(
        const _Float16* __restrict__ aH, const _Float16* __restrict__ cH,
        const _Float16* __restrict__ w2L,
        const float* __restrict__ b2, const float* __restrict__ W3,
        const float* __restrict__ b3, float* __restrict__ out) {
    const int jt = blockIdx.x, it = blockIdx.y, b = blockIdx.z;
    const int i0 = it * TI, j0 = jt * TJ;

    __shared__ __align__(16) _Float16 sa[TI * H_DIM];   // 8 KB
    __shared__ __align__(16) _Float16 sc[TJ * H_DIM];   // 8 KB
    __shared__ float spart[4][64];                      // 1 KB

    const int tid = threadIdx.x;
    const int wave = tid >> 6, lane = tid & 63;
    const int quad = lane >> 4, l16 = lane & 15;
    const int wn = wave;            // 4 waves split N
    const int nb = wn * 64;

    // ---- stage a rows (8) and c rows (8), full K, XOR-swizzled, async ----
#pragma unroll
    for (int rr0 = 0; rr0 < 2; rr0++) {
        int rr = rr0 * 4 + wave;
        int gc = (lane & ~7) | ((lane & 7) ^ (rr & 7));
        __builtin_amdgcn_global_load_lds(
            (const AS1 unsigned int*)&aH[((size_t)(b * S_DIM + i0 + rr)) * H_DIM + gc * 8],
            (AS3 unsigned int*)&sa[rr * H_DIM], 16, 0, 0);
        __builtin_amdgcn_global_load_lds(
            (const AS1 unsigned int*)&cH[((size_t)(b * S_DIM + j0 + rr)) * H_DIM + gc * 8],
            (AS3 unsigned int*)&sc[rr * H_DIM], 16, 0, 0);
    }

    // row r of tile: i_local = r>>3, j_local = r&7.  jlrow = l16&7 (uniform over mt).
    int ilrow[4];
#pragma unroll
    for (int mt = 0; mt < 4; mt++) ilrow[mt] = (mt * 16 + l16) >> 3;
    const int jl = l16 & 7;

    f32x4 acc[4][4];
#pragma unroll
    for (int mt = 0; mt < 4; mt++)
#pragma unroll
        for (int nt = 0; nt < 4; nt++) acc[mt][nt] = (f32x4)0.f;

    // B-frag base offsets (fragment-major layout: chunk (gcb,n) at (gcb*256+n)*16B)
    const _Float16* bbase[4];
#pragma unroll
    for (int nt = 0; nt < 4; nt++) bbase[nt] = &w2L[((size_t)quad * 256 + nb + nt * 16 + l16) * 8];

    // prefetch B for ks=0
    half8 bnxt[4];
#pragma unroll
    for (int nt = 0; nt < 4; nt++) bnxt[nt] = *(const half8*)&bbase[nt][0];

    __syncthreads();   // sa/sc staged

#pragma unroll
    for (int ks = 0; ks < 16; ks++) {
        half8 bf[4];
#pragma unroll
        for (int nt = 0; nt < 4; nt++) bf[nt] = bnxt[nt];
        if (ks < 15) {
#pragma unroll
            for (int nt = 0; nt < 4; nt++)
                bnxt[nt] = *(const half8*)&bbase[nt][(size_t)(ks + 1) * 4 * 256 * 8];
        }
        const int gcb = ks * 4 + quad;
        const int slotC = (gcb & ~7) | ((gcb & 7) ^ jl);
        half8 vc = *(const half8*)&sc[jl * H_DIM + slotC * 8];
        half8 af[4];
#pragma unroll
        for (int mt = 0; mt < 4; mt++) {
            int slotA = (gcb & ~7) | ((gcb & 7) ^ (ilrow[mt] & 7));
            half8 va = *(const half8*)&sa[ilrow[mt] * H_DIM + slotA * 8];
            half8 h = va + vc;
#pragma unroll
            for (int e = 0; e < 8; e++)
                h[e] = h[e] > (_Float16)0.f ? h[e] : (_Float16)0.f;
            af[mt] = h;
        }
#pragma unroll
        for (int nt = 0; nt < 4; nt++)
#pragma unroll
            for (int mt = 0; mt < 4; mt++)
                acc[mt][nt] = __builtin_amdgcn_mfma_f32_16x16x32_f16(af[mt], bf[nt],
                                                                     acc[mt][nt], 0, 0, 0);
    }

    // ---- fused epilogue: h2 = relu(acc+b2); partial logit = h2 . W3 ----
    float b2v[4], w3v[4];
#pragma unroll
    for (int nt = 0; nt < 4; nt++) {
        int n = nb + nt * 16 + l16;
        b2v[nt] = b2[n];
        w3v[nt] = W3[n];
    }
    float ps[4][4];
#pragma unroll
    for (int mt = 0; mt < 4; mt++)
#pragma unroll
        for (int r = 0; r < 4; r++) {
            float s = 0.f;
#pragma unroll
            for (int nt = 0; nt < 4; nt++) {
                float v = acc[mt][nt][r] + b2v[nt];
                v = v > 0.f ? v : 0.f;
                s += v * w3v[nt];
            }
            ps[mt][r] = s;
        }
#pragma unroll
    for (int mt = 0; mt < 4; mt++)
#pragma unroll
        for (int r = 0; r < 4; r++) {
            float s = ps[mt][r];
            s += __shfl_xor(s, 8, 16);
            s += __shfl_xor(s, 4, 16);
            s += __shfl_xor(s, 2, 16);
            s += __shfl_xor(s, 1, 16);
            ps[mt][r] = s;
        }
    if (l16 == 0) {
#pragma unroll
        for (int mt = 0; mt < 4; mt++)
#pragma unroll
            for (int r = 0; r < 4; r++)
                spart[wn][mt * 16 + quad * 4 + r] = ps[mt][r];
    }
    __syncthreads();
    if (tid < 64) {
        float tot = spart[0][tid] + spart[1][tid] + spart[2][tid] + spart[3][tid] + b3[0];
        float sg = 1.f / (1.f + __expf(-tot));
        int i = i0 + (tid >> 3), j = j0 + (tid & 7);
        out[(size_t)b * S_DIM * S_DIM + (size_t)i * S_DIM + j] = sg;
    }
}

extern "C" void kernel_launch(void* const* d_in, const int* in_sizes, int n_in,
                              void* d_out, int out_size, void* d_ws, size_t ws_size,
                              hipStream_t stream) {
    const float* feats = (const float*)d_in[0];
    const float* W1 = (const float*)d_in[1];
    const float* b1 = (const float*)d_in[2];
    const float* W2 = (const float*)d_in[3];
    const float* b2 = (const float*)d_in[4];
    const float* W3 = (const float*)d_in[5];
    const float* b3 = (const float*)d_in[6];
    float* out = (float*)d_out;

    const int B = in_sizes[0] / (S_DIM * H_DIM);   // = 2
    const int M = B * S_DIM;                       // 1024

    char* ws = (char*)d_ws;
    _Float16* f16  = (_Float16*)ws;                 // [1024][512] = 1 MB
    _Float16* aH   = (_Float16*)(ws + (1 << 20));   // [1024][512] = 1 MB
    _Float16* cH   = (_Float16*)(ws + (2 << 20));   // [1024][512] = 1 MB
    _Float16* w1L  = (_Float16*)(ws + (3 << 20));   // 64*1024*16B = 1 MB
    _Float16* w2L  = (_Float16*)(ws + (4 << 20));   // 64*256*16B = 256 KB

    convert_feats_kernel<<<M * H_DIM / 1024, 256, 0, stream>>>(feats, f16);
    convert_w1_kernel<<<256, 256, 0, stream>>>(W1, w1L);
    convert_w2_kernel<<<64, 256, 0, stream>>>(W2, w2L);
    prep_mfma_kernel<<<dim3(16, M / 64), 256, 0, stream>>>(f16, w1L, b1, aH, cH);
    pair_kernel<<<dim3(S_DIM / TJ, S_DIM / TI, B), 256, 0, stream>>>(aH, cH, w2L, b2, W3, b3, out);
}

// Round 3
// 208.965 us; speedup vs baseline: 1.3612x; 1.0974x over previous
//
#include <hip/hip_runtime.h>

#define S_DIM 512
#define H_DIM 512
#define NH 256
#define TI 8
#define TJ 8

#define AS1 __attribute__((address_space(1)))
#define AS3 __attribute__((address_space(3)))

typedef _Float16 half8 __attribute__((ext_vector_type(8)));
typedef _Float16 half4 __attribute__((ext_vector_type(4)));
typedef float f32x4 __attribute__((ext_vector_type(4)));

__device__ __forceinline__ int swz(int r) { return ((r & 1) << 2) | (r >> 1); }  // perm of 0..7

// ---------------- k0: fused converts ----------------
// blocks [0,512): feats fp32->f16 ; [512,768): W1 -> fragment-major f16 ; [768,832): W2 -> frag-major
__global__ __launch_bounds__(256) void convert_all_kernel(const float* __restrict__ feats,
        const float* __restrict__ W1, const float* __restrict__ W2,
        _Float16* __restrict__ f16, _Float16* __restrict__ w1L, _Float16* __restrict__ w2L) {
    int blk = blockIdx.x;
    if (blk < 512) {
        int t = blk * 256 + threadIdx.x;           // 131072 threads, 4 elems each
        float4 v = ((const float4*)feats)[t];
        half4 h;
        h.x = (_Float16)v.x; h.y = (_Float16)v.y; h.z = (_Float16)v.z; h.w = (_Float16)v.w;
        ((half4*)f16)[t] = h;
    } else if (blk < 768) {
        int t = (blk - 512) * 256 + threadIdx.x;   // 65536
        int gcb = t >> 10, n = t & 1023;
        const float* src = (n < H_DIM) ? &W1[(size_t)(gcb * 8) * H_DIM + n]
                                       : &W1[(size_t)(H_DIM + gcb * 8) * H_DIM + (n - H_DIM)];
        half8 v;
#pragma unroll
        for (int j = 0; j < 8; j++) v[j] = (_Float16)src[(size_t)j * H_DIM];
        *(half8*)&w1L[((size_t)gcb * 1024 + n) * 8] = v;
    } else {
        int t = (blk - 768) * 256 + threadIdx.x;   // 16384
        int gcb = t >> 8, n = t & 255;
        half8 v;
#pragma unroll
        for (int j = 0; j < 8; j++) v[j] = (_Float16)W2[(size_t)(gcb * 8 + j) * NH + n];
        *(half8*)&w2L[((size_t)gcb * 256 + n) * 8] = v;
    }
}

// ---------------- k1: prep GEMM  [1024 x 512] @ [512 x 1024] f16 MFMA --------------
__global__ __launch_bounds__(256) void prep_mfma_kernel(const _Float16* __restrict__ f16,
        const _Float16* __restrict__ w1L, const float* __restrict__ b1,
        _Float16* __restrict__ aH, _Float16* __restrict__ cH) {
    const int n0 = blockIdx.x * 64, m0 = blockIdx.y * 64;
    const int tid = threadIdx.x, wave = tid >> 6, lane = tid & 63;
    const int quad = lane >> 4, l16 = lane & 15;
    const int wm = wave >> 1, wn = wave & 1;
    int mrow[2], ncol[2];
#pragma unroll
    for (int mt = 0; mt < 2; mt++) mrow[mt] = m0 + wm * 32 + mt * 16 + l16;
#pragma unroll
    for (int nt = 0; nt < 2; nt++) ncol[nt] = n0 + wn * 32 + nt * 16 + l16;
    f32x4 acc[2][2];
#pragma unroll
    for (int mt = 0; mt < 2; mt++)
#pragma unroll
        for (int nt = 0; nt < 2; nt++) acc[mt][nt] = (f32x4)0.f;
#pragma unroll
    for (int ks = 0; ks < 16; ks++) {
        int gcb = ks * 4 + quad;
        half8 af[2], bf[2];
#pragma unroll
        for (int mt = 0; mt < 2; mt++)
            af[mt] = *(const half8*)&f16[(size_t)mrow[mt] * H_DIM + gcb * 8];
#pragma unroll
        for (int nt = 0; nt < 2; nt++)
            bf[nt] = *(const half8*)&w1L[((size_t)gcb * 1024 + ncol[nt]) * 8];
#pragma unroll
        for (int nt = 0; nt < 2; nt++)
#pragma unroll
            for (int mt = 0; mt < 2; mt++)
                acc[mt][nt] = __builtin_amdgcn_mfma_f32_16x16x32_f16(af[mt], bf[nt],
                                                                     acc[mt][nt], 0, 0, 0);
    }
    const bool first_half = (n0 < H_DIM);
#pragma unroll
    for (int nt = 0; nt < 2; nt++) {
        float bias = first_half ? b1[ncol[nt]] : 0.f;
#pragma unroll
        for (int mt = 0; mt < 2; mt++)
#pragma unroll
            for (int r = 0; r < 4; r++) {
                int m = m0 + wm * 32 + mt * 16 + quad * 4 + r;
                float v = acc[mt][nt][r] + bias;
                if (first_half) aH[(size_t)m * H_DIM + ncol[nt]] = (_Float16)v;
                else            cH[(size_t)m * H_DIM + (ncol[nt] - H_DIM)] = (_Float16)v;
            }
    }
}

// ---------------- k2: pair GEMM, barrier-free K-loop, B from global ----------------
// grid (64,64,B). block 256 = 4 waves splitting N (4x64). Block M-tile = 64 pairs (8i x 8j).
__global__ __launch_bounds__(256, 4) void pair_kernel(
        const _Float16* __restrict__ aH, const _Float16* __restrict__ cH,
        const _Float16* __restrict__ w2L,
        const float* __restrict__ b2, const float* __restrict__ W3,
        const float* __restrict__ b3, float* __restrict__ out) {
    const int jt = blockIdx.x, it = blockIdx.y, b = blockIdx.z;
    const int i0 = it * TI, j0 = jt * TJ;

    __shared__ __align__(16) _Float16 sa[TI * H_DIM];   // 8 KB
    __shared__ __align__(16) _Float16 sc[TJ * H_DIM];   // 8 KB
    __shared__ float spart[4][64];                      // 1 KB

    const int tid = threadIdx.x;
    const int wave = tid >> 6, lane = tid & 63;
    const int quad = lane >> 4, l16 = lane & 15;
    const int wn = wave;
    const int nb = wn * 64;

    // ---- stage a rows (8) and c rows (8), swizzled: LDS slot s of row r holds
    // global chunk s ^ swz(r&7)  (DMA lane i -> LDS slot i) ----
#pragma unroll
    for (int rr0 = 0; rr0 < 2; rr0++) {
        int rr = rr0 * 4 + wave;
        int gc = lane ^ swz(rr & 7);
        __builtin_amdgcn_global_load_lds(
            (const AS1 unsigned int*)&aH[((size_t)(b * S_DIM + i0 + rr)) * H_DIM + gc * 8],
            (AS3 unsigned int*)&sa[rr * H_DIM], 16, 0, 0);
        __builtin_amdgcn_global_load_lds(
            (const AS1 unsigned int*)&cH[((size_t)(b * S_DIM + j0 + rr)) * H_DIM + gc * 8],
            (AS3 unsigned int*)&sc[rr * H_DIM], 16, 0, 0);
    }

    int saoff[4], swzA[4];
#pragma unroll
    for (int mt = 0; mt < 4; mt++) {
        int il = (mt * 16 + l16) >> 3;
        saoff[mt] = il * H_DIM;
        swzA[mt] = swz(il);
    }
    const int jl = l16 & 7;
    const int scoff = jl * H_DIM, swzC = swz(jl);

    f32x4 acc[4][4];
#pragma unroll
    for (int mt = 0; mt < 4; mt++)
#pragma unroll
        for (int nt = 0; nt < 4; nt++) acc[mt][nt] = (f32x4)0.f;

    // single B pointer, walked +4*256 chunks (16 KB) per ks; nt offset = 16 chunks (256 B imm)
    const _Float16* bp = &w2L[((size_t)quad * 256 + nb + l16) * 8];

    half8 bnxt[4];
#pragma unroll
    for (int nt = 0; nt < 4; nt++) bnxt[nt] = *(const half8*)&bp[nt * 16 * 8];

    __syncthreads();   // sa/sc staged (drains DMA)

#pragma unroll
    for (int ks = 0; ks < 16; ks++) {
        half8 bf[4];
#pragma unroll
        for (int nt = 0; nt < 4; nt++) bf[nt] = bnxt[nt];
        if (ks < 15) {
            const _Float16* bn = bp + (size_t)4 * 256 * 8;
#pragma unroll
            for (int nt = 0; nt < 4; nt++) bnxt[nt] = *(const half8*)&bn[nt * 16 * 8];
            bp = bn;
        }
        const int gcb = ks * 4 + quad;
        half8 vc = *(const half8*)&sc[scoff + (gcb ^ swzC) * 8];
        half8 af[4];
#pragma unroll
        for (int mt = 0; mt < 4; mt++) {
            half8 va = *(const half8*)&sa[saoff[mt] + (gcb ^ swzA[mt]) * 8];
            af[mt] = __builtin_elementwise_max(va + vc, (half8)(_Float16)0.f);
        }
#pragma unroll
        for (int nt = 0; nt < 4; nt++)
#pragma unroll
            for (int mt = 0; mt < 4; mt++)
                acc[mt][nt] = __builtin_amdgcn_mfma_f32_16x16x32_f16(af[mt], bf[nt],
                                                                     acc[mt][nt], 0, 0, 0);
    }

    // ---- fused epilogue: h2 = relu(acc+b2); partial logit = h2 . W3 ----
    float b2v[4], w3v[4];
#pragma unroll
    for (int nt = 0; nt < 4; nt++) {
        int n = nb + nt * 16 + l16;
        b2v[nt] = b2[n];
        w3v[nt] = W3[n];
    }
    float ps[4][4];
#pragma unroll
    for (int mt = 0; mt < 4; mt++)
#pragma unroll
        for (int r = 0; r < 4; r++) {
            float s = 0.f;
#pragma unroll
            for (int nt = 0; nt < 4; nt++) {
                float v = acc[mt][nt][r] + b2v[nt];
                v = v > 0.f ? v : 0.f;
                s += v * w3v[nt];
            }
            ps[mt][r] = s;
        }
#pragma unroll
    for (int mt = 0; mt < 4; mt++)
#pragma unroll
        for (int r = 0; r < 4; r++) {
            float s = ps[mt][r];
            s += __shfl_xor(s, 8, 16);
            s += __shfl_xor(s, 4, 16);
            s += __shfl_xor(s, 2, 16);
            s += __shfl_xor(s, 1, 16);
            ps[mt][r] = s;
        }
    if (l16 == 0) {
#pragma unroll
        for (int mt = 0; mt < 4; mt++)
#pragma unroll
            for (int r = 0; r < 4; r++)
                spart[wn][mt * 16 + quad * 4 + r] = ps[mt][r];
    }
    __syncthreads();
    if (tid < 64) {
        float tot = spart[0][tid] + spart[1][tid] + spart[2][tid] + spart[3][tid] + b3[0];
        float sg = 1.f / (1.f + __expf(-tot));
        int i = i0 + (tid >> 3), j = j0 + (tid & 7);
        out[(size_t)b * S_DIM * S_DIM + (size_t)i * S_DIM + j] = sg;
    }
}

extern "C" void kernel_launch(void* const* d_in, const int* in_sizes, int n_in,
                              void* d_out, int out_size, void* d_ws, size_t ws_size,
                              hipStream_t stream) {
    const float* feats = (const float*)d_in[0];
    const float* W1 = (const float*)d_in[1];
    const float* b1 = (const float*)d_in[2];
    const float* W2 = (const float*)d_in[3];
    const float* b2 = (const float*)d_in[4];
    const float* W3 = (const float*)d_in[5];
    const float* b3 = (const float*)d_in[6];
    float* out = (float*)d_out;

    const int B = in_sizes[0] / (S_DIM * H_DIM);   // = 2
    const int M = B * S_DIM;                       // 1024

    char* ws = (char*)d_ws;
    _Float16* f16  = (_Float16*)ws;                 // [1024][512] = 1 MB
    _Float16* aH   = (_Float16*)(ws + (1 << 20));   // [1024][512] = 1 MB
    _Float16* cH   = (_Float16*)(ws + (2 << 20));   // [1024][512] = 1 MB
    _Float16* w1L  = (_Float16*)(ws + (3 << 20));   // 1 MB
    _Float16* w2L  = (_Float16*)(ws + (4 << 20));   // 256 KB

    convert_all_kernel<<<832, 256, 0, stream>>>(feats, W1, W2, f16, w1L, w2L);
    prep_mfma_kernel<<<dim3(16, M / 64), 256, 0, stream>>>(f16, w1L, b1, aH, cH);
    pair_kernel<<<dim3(S_DIM / TJ, S_DIM / TI, B), 256, 0, stream>>>(aH, cH, w2L, b2, W3, b3, out);
}